// Round 1
// baseline (1095.127 us; speedup 1.0000x reference)
//
#include <hip/hip_runtime.h>
#include <hip/hip_bf16.h>
#include <cstddef>

// Problem constants (B,T,I,H,K) = (32,1024,512,512,2)
#define B_  32
#define T_  1024
#define I_  512
#define H_  512
#define M_  (B_ * T_)      // 32768
#define KK_ (2 * I_)       // 1024 reduction dim (two taps)

// ---------------------------------------------------------------------------
// Kernel 0: transpose weights W[h][i][k] -> Wt[kk][h], kk = half*I + i
// ---------------------------------------------------------------------------
__global__ __launch_bounds__(512) void transpose_w(const float* __restrict__ W,
                                                   float* __restrict__ Wt) {
    int idx = blockIdx.x * 512 + threadIdx.x;      // 0 .. 524287
    int kk = idx >> 9;                              // 0..1023
    int h  = idx & 511;
    int i    = kk & 511;
    int half = kk >> 9;
    Wt[idx] = W[h * (I_ * 2) + i * 2 + half];
}

// ---------------------------------------------------------------------------
// Kernel 1: dual-gate GEMM.
//   rawG[m][h] = sum_kk A[m][kk] * WtG[kk][h]
//   A[m][kk]  = half==0 ? (t>0 ? x[m-1][i] : 0) : x[m][i]
// 64x64 tile, BK=16, 256 threads, 4x4 microtile, both gates share A tile.
// ---------------------------------------------------------------------------
#define BM 64
#define BN 64
#define BK 16
#define LDP 68   // padded LDS leading dim (272B rows, 16B-aligned)

__global__ __launch_bounds__(256) void gates_gemm(
        const float* __restrict__ x,     // [M_][I_]
        const float* __restrict__ WtF,   // [KK_][H_]
        const float* __restrict__ WtZ,   // [KK_][H_]
        float* __restrict__ rawF,        // [M_][H_]
        float* __restrict__ rawZ) {
    __shared__ float As [BK][LDP];
    __shared__ float Bfs[BK][LDP];
    __shared__ float Bzs[BK][LDP];

    const int m0  = blockIdx.y * BM;
    const int n0  = blockIdx.x * BN;
    const int tid = threadIdx.x;

    const int tx = tid & 15;   // n direction (x4)
    const int ty = tid >> 4;   // m direction (x4)

    // A-load mapping: each thread loads one float4 of one A row
    const int arow = tid >> 2;            // 0..63
    const int acol = (tid & 3) * 4;       // 0,4,8,12
    const int m    = m0 + arow;
    const int t    = m & (T_ - 1);

    // B-load mapping: each thread loads one float4 of one Wt row
    const int kr = tid >> 4;              // 0..15
    const int nc = (tid & 15) * 4;        // 0..60

    float accF[4][4] = {{0.f}};
    float accZ[4][4] = {{0.f}};

    for (int kk0 = 0; kk0 < KK_; kk0 += BK) {
        // ---- stage A tile ----
        const int kk   = kk0 + acol;
        const int half = kk >> 9;
        const int i    = kk & 511;
        float4 av;
        if (half == 0) {
            if (t > 0) av = *(const float4*)&x[(size_t)(m - 1) * I_ + i];
            else       av = make_float4(0.f, 0.f, 0.f, 0.f);
        } else {
            av = *(const float4*)&x[(size_t)m * I_ + i];
        }
        As[acol + 0][arow] = av.x;
        As[acol + 1][arow] = av.y;
        As[acol + 2][arow] = av.z;
        As[acol + 3][arow] = av.w;

        // ---- stage B tiles (coalesced thanks to transpose) ----
        *(float4*)&Bfs[kr][nc] = *(const float4*)&WtF[(size_t)(kk0 + kr) * H_ + n0 + nc];
        *(float4*)&Bzs[kr][nc] = *(const float4*)&WtZ[(size_t)(kk0 + kr) * H_ + n0 + nc];

        __syncthreads();

        #pragma unroll
        for (int k = 0; k < BK; ++k) {
            float4 a4  = *(const float4*)&As [k][ty * 4];
            float4 bf4 = *(const float4*)&Bfs[k][tx * 4];
            float4 bz4 = *(const float4*)&Bzs[k][tx * 4];
            float ar[4]  = {a4.x,  a4.y,  a4.z,  a4.w};
            float bfr[4] = {bf4.x, bf4.y, bf4.z, bf4.w};
            float bzr[4] = {bz4.x, bz4.y, bz4.z, bz4.w};
            #pragma unroll
            for (int r = 0; r < 4; ++r) {
                #pragma unroll
                for (int c = 0; c < 4; ++c) {
                    accF[r][c] = fmaf(ar[r], bfr[c], accF[r][c]);
                    accZ[r][c] = fmaf(ar[r], bzr[c], accZ[r][c]);
                }
            }
        }
        __syncthreads();
    }

    // ---- epilogue ----
    #pragma unroll
    for (int r = 0; r < 4; ++r) {
        const size_t row = (size_t)(m0 + ty * 4 + r);
        float4 vf = make_float4(accF[r][0], accF[r][1], accF[r][2], accF[r][3]);
        float4 vz = make_float4(accZ[r][0], accZ[r][1], accZ[r][2], accZ[r][3]);
        *(float4*)&rawF[row * H_ + n0 + tx * 4] = vf;
        *(float4*)&rawZ[row * H_ + n0 + tx * 4] = vz;
    }
}

// ---------------------------------------------------------------------------
// Kernel 2: sigmoid + sequential scan over t, one thread per (b,h).
//   h[t] = f*h[t-1] + (1-f)*z = fma(f, h-z, z)
// ---------------------------------------------------------------------------
__global__ __launch_bounds__(256) void scan_kernel(
        const float* __restrict__ rawF, const float* __restrict__ rawZ,
        const float* __restrict__ biasF, const float* __restrict__ biasZ,
        float* __restrict__ out) {
    const int g = blockIdx.x * 256 + threadIdx.x;  // 0..16383
    const int b = g >> 9;        // / H_
    const int h = g & (H_ - 1);
    const float bfv = biasF[h];
    const float bzv = biasZ[h];
    float hs = 0.f;
    size_t base = (size_t)b * T_ * H_ + h;
    #pragma unroll 4
    for (int t = 0; t < T_; ++t) {
        const size_t idx = base + (size_t)t * H_;
        float rf = rawF[idx] + bfv;
        float rz = rawZ[idx] + bzv;
        float f = 1.f / (1.f + __expf(-rf));
        float z = 1.f / (1.f + __expf(-rz));
        hs = fmaf(f, hs - z, z);
        out[idx] = hs;
    }
}

// ---------------------------------------------------------------------------
extern "C" void kernel_launch(void* const* d_in, const int* in_sizes, int n_in,
                              void* d_out, int out_size, void* d_ws, size_t ws_size,
                              hipStream_t stream) {
    const float* x     = (const float*)d_in[0];  // inputs  [B,T,I]
    // d_in[1] init_state: unused by the reference
    const float* Wz    = (const float*)d_in[2];  // [H,I,K]
    const float* bz    = (const float*)d_in[3];  // [H]
    const float* Wf    = (const float*)d_in[4];  // [H,I,K]
    const float* bf    = (const float*)d_in[5];  // [H]
    float* out = (float*)d_out;

    char* ws = (char*)d_ws;
    const size_t RAW_BYTES = (size_t)M_ * H_ * sizeof(float);   // 64 MB
    const size_t WT_BYTES  = (size_t)KK_ * H_ * sizeof(float);  // 2 MB
    float* rawF = (float*)(ws);
    float* rawZ = (float*)(ws + RAW_BYTES);
    float* WtF  = (float*)(ws + 2 * RAW_BYTES);
    float* WtZ  = (float*)(ws + 2 * RAW_BYTES + WT_BYTES);

    transpose_w<<<1024, 512, 0, stream>>>(Wf, WtF);
    transpose_w<<<1024, 512, 0, stream>>>(Wz, WtZ);

    dim3 grid(H_ / BN, M_ / BM);   // (8, 512)
    gates_gemm<<<grid, 256, 0, stream>>>(x, WtF, WtZ, rawF, rawZ);

    scan_kernel<<<(B_ * H_) / 256, 256, 0, stream>>>(rawF, rawZ, bf, bz, out);
}

// Round 2
// 330.760 us; speedup vs baseline: 3.3109x; 3.3109x over previous
//
#include <hip/hip_runtime.h>
#include <hip/hip_bf16.h>
#include <cstddef>
#include <cstdint>

// (B,T,I,H,K) = (32,1024,512,512,2)
#define B_  32
#define T_  1024
#define I_  512
#define H_  512
#define M_  (B_ * T_)     // 32768
#define KK_ 1024          // 2 taps * I
#define NN_ 1024          // concat F|Z columns

typedef __bf16 bf16x8  __attribute__((ext_vector_type(8)));
typedef float  floatx4 __attribute__((ext_vector_type(4)));

// fp32 -> bf16 RNE, branch-free (inputs are finite)
__device__ __forceinline__ unsigned short f2bf(float f) {
    uint32_t u = __float_as_uint(f);
    return (unsigned short)((u + 0x7FFFu + ((u >> 16) & 1u)) >> 16);
}

// async 16B global->LDS (dest = wave-uniform base + lane*16)
#define GLL(src, dst) __builtin_amdgcn_global_load_lds( \
    (const __attribute__((address_space(1))) void*)(src), \
    (__attribute__((address_space(3))) void*)(dst), 16, 0, 0)

// ---------------------------------------------------------------------------
// Kernel: build A matrix. Ab[m][kk] bf16, kk<512 -> x[m-1][kk] (0 at t==0),
// kk>=512 -> x[m][kk-512]. 4 elements/thread.
// ---------------------------------------------------------------------------
__global__ __launch_bounds__(256) void build_a(const float* __restrict__ x,
                                               unsigned short* __restrict__ Ab) {
    int g = blockIdx.x * 256 + threadIdx.x;
    int idx4 = g << 2;                 // element index in Ab
    int m    = idx4 >> 10;
    int kk   = idx4 & 1023;
    int half = kk >> 9;
    int i    = kk & 511;
    int t    = m & (T_ - 1);
    float4 v = make_float4(0.f, 0.f, 0.f, 0.f);
    if (half == 0) {
        if (t > 0) v = *(const float4*)&x[(size_t)(m - 1) * I_ + i];
    } else {
        v = *(const float4*)&x[(size_t)m * I_ + i];
    }
    ushort4 o;
    o.x = f2bf(v.x); o.y = f2bf(v.y); o.z = f2bf(v.z); o.w = f2bf(v.w);
    *(ushort4*)&Ab[(size_t)idx4] = o;
}

// ---------------------------------------------------------------------------
// Kernel: pack weights to the exact per-tile LDS order (bf16).
// Wp[kt][n][kw]: n<512 -> Wf col, n>=512 -> Wz col; kk=kt*32+kw;
// tap = kk>>9 (tap0 multiplies x[t-1]); i = kk&511. W layout [H][I][2].
// ---------------------------------------------------------------------------
__global__ __launch_bounds__(256) void pack_w(const float* __restrict__ Wf,
                                              const float* __restrict__ Wz,
                                              unsigned short* __restrict__ Wp) {
    int e = blockIdx.x * 256 + threadIdx.x;    // 0 .. 1048575
    int kt  = e >> 15;
    int n   = (e >> 5) & 1023;
    int kw  = e & 31;
    int kk  = kt * 32 + kw;
    int tap = kk >> 9;
    int i   = kk & 511;
    int h   = n & 511;
    const float* G = (n < 512) ? Wf : Wz;
    Wp[e] = f2bf(G[h * (I_ * 2) + i * 2 + tap]);
}

// ---------------------------------------------------------------------------
// Kernel: MFMA GEMM. raw[m][n] = sum_kk Ab[m][kk] * Wp[.][n][.]
// 128x128 tile, BK=32, 256 thr (2x2 waves, each 64x64 via 4x4 mfma 16x16x32).
// Columns n<512 -> rawF (ws), n>=512 -> rawZ (d_out, reused as scratch).
// XOR swizzle on LDS chunk index so frag ds_read_b128 is 2-way (free).
// ---------------------------------------------------------------------------
__global__ __launch_bounds__(256) void mfma_gemm(
        const unsigned short* __restrict__ Ab,   // [M_][1024]
        const unsigned short* __restrict__ Wp,   // [32][1024][32]
        float* __restrict__ rawF,                // [M_][512]
        float* __restrict__ rawZ) {              // [M_][512]
    __shared__ unsigned short smem[8192];        // A: [0,4096), B: [4096,8192)

    const int tid  = threadIdx.x;
    const int lane = tid & 63;
    const int wave = tid >> 6;       // 0..3
    const int wm   = wave >> 1, wn = wave & 1;
    const int lm   = lane & 15, quad = lane >> 4;
    const int m0   = blockIdx.y * 128;
    const int n0   = blockIdx.x * 128;

    // ---- staging: 512 16B-chunks per tile; this thread's two chunk ids ----
    const int c0 = wave * 128 + lane;            // issue 0
    const int c1 = c0 + 64;                      // issue 1
    const int r0 = c0 >> 2, q0 = (c0 & 3) ^ ((r0 >> 2) & 3);
    const int r1 = c1 >> 2, q1 = (c1 & 3) ^ ((r1 >> 2) & 3);

    const unsigned short* srcA0 = Ab + (size_t)(m0 + r0) * KK_ + q0 * 8;
    const unsigned short* srcA1 = Ab + (size_t)(m0 + r1) * KK_ + q1 * 8;
    const unsigned short* srcB0 = Wp + (size_t)(n0 + r0) * 32 + q0 * 8;
    const unsigned short* srcB1 = Wp + (size_t)(n0 + r1) * 32 + q1 * 8;

    unsigned short* dA0 = smem + wave * 1024;          // chunk (wave*128)*8
    unsigned short* dA1 = smem + wave * 1024 + 512;
    unsigned short* dB0 = smem + 4096 + wave * 1024;
    unsigned short* dB1 = smem + 4096 + wave * 1024 + 512;

    // ---- fragment LDS element-offsets (constant over kt) ----
    int offA[4], offB[4];
    #pragma unroll
    for (int r = 0; r < 4; ++r) {
        int ml = wm * 64 + r * 16 + lm;
        offA[r] = (4 * ml + (quad ^ ((ml >> 2) & 3))) * 8;
    }
    #pragma unroll
    for (int c = 0; c < 4; ++c) {
        int nl = wn * 64 + c * 16 + lm;
        offB[c] = 4096 + (4 * nl + (quad ^ ((nl >> 2) & 3))) * 8;
    }

    floatx4 acc[4][4] = {};

    for (int kt = 0; kt < 32; ++kt) {
        const int kk0 = kt * 32;
        GLL(srcA0 + kk0, dA0);
        GLL(srcA1 + kk0, dA1);
        GLL(srcB0 + (size_t)kt * 32768, dB0);
        GLL(srcB1 + (size_t)kt * 32768, dB1);
        __syncthreads();   // compiler emits vmcnt(0) drain before barrier

        bf16x8 af[4], bfr[4];
        #pragma unroll
        for (int r = 0; r < 4; ++r) af[r]  = *(const bf16x8*)(smem + offA[r]);
        #pragma unroll
        for (int c = 0; c < 4; ++c) bfr[c] = *(const bf16x8*)(smem + offB[c]);

        #pragma unroll
        for (int r = 0; r < 4; ++r)
            #pragma unroll
            for (int c = 0; c < 4; ++c)
                acc[r][c] = __builtin_amdgcn_mfma_f32_16x16x32_bf16(
                                af[r], bfr[c], acc[r][c], 0, 0, 0);
        __syncthreads();   // protect LDS before next stage
    }

    // ---- epilogue: C/D layout col=lane&15, row=quad*4+reg ----
    float* base = (n0 < 512) ? rawF : rawZ;
    const int col0 = (n0 & 511) + wn * 64 + lm;
    #pragma unroll
    for (int r = 0; r < 4; ++r) {
        #pragma unroll
        for (int v = 0; v < 4; ++v) {
            const size_t row = (size_t)(m0 + wm * 64 + r * 16 + quad * 4 + v);
            #pragma unroll
            for (int c = 0; c < 4; ++c)
                base[row * H_ + col0 + c * 16] = acc[r][c][v];
        }
    }
}

// ---------------------------------------------------------------------------
// Scan: h[t] = f*h[t-1] + (1-f)*z, split T into 32 chunks of 32.
// Pass 1: per (b,h,chunk) compute affine composition (A = prod f, C).
// ---------------------------------------------------------------------------
__global__ __launch_bounds__(256) void scan_pass1(
        const float* __restrict__ rawF, const float* __restrict__ rawZ,
        const float* __restrict__ biasF, const float* __restrict__ biasZ,
        float* __restrict__ chA, float* __restrict__ chC) {
    int g  = blockIdx.x * 256 + threadIdx.x;   // 524288
    int h  = g & 511;
    int b  = (g >> 9) & 31;
    int ck = g >> 14;
    const float bfv = biasF[h], bzv = biasZ[h];
    size_t base = ((size_t)(b * T_ + ck * 32)) * H_ + h;
    float A = 1.f, C = 0.f;
    #pragma unroll 8
    for (int s = 0; s < 32; ++s) {
        float rf = rawF[base + (size_t)s * H_] + bfv;
        float rz = rawZ[base + (size_t)s * H_] + bzv;
        float f = __builtin_amdgcn_rcpf(1.f + __expf(-rf));
        float z = __builtin_amdgcn_rcpf(1.f + __expf(-rz));
        A *= f;
        C = fmaf(f, C - z, z);
    }
    chA[ck * 16384 + (b << 9) + h] = A;
    chC[ck * 16384 + (b << 9) + h] = C;
}

// Pass 2: scan the 32 chunk compositions per (b,h); Hin[ck] = h before chunk.
__global__ __launch_bounds__(256) void scan_pass2(
        const float* __restrict__ chA, const float* __restrict__ chC,
        float* __restrict__ Hin) {
    int bh = blockIdx.x * 256 + threadIdx.x;   // 16384
    float H = 0.f;
    #pragma unroll
    for (int ck = 0; ck < 32; ++ck) {
        Hin[ck * 16384 + bh] = H;
        float A = chA[ck * 16384 + bh];
        float C = chC[ck * 16384 + bh];
        H = fmaf(A, H, C);
    }
}

// Pass 3: replay chunk with correct h_in, write hidden. rawZ==out: each
// element is read then written by the same thread (safe).
__global__ __launch_bounds__(256) void scan_pass3(
        const float* __restrict__ rawF, const float* __restrict__ rawZ,
        const float* __restrict__ biasF, const float* __restrict__ biasZ,
        const float* __restrict__ Hin, float* __restrict__ out) {
    int g  = blockIdx.x * 256 + threadIdx.x;
    int h  = g & 511;
    int b  = (g >> 9) & 31;
    int ck = g >> 14;
    const float bfv = biasF[h], bzv = biasZ[h];
    size_t base = ((size_t)(b * T_ + ck * 32)) * H_ + h;
    float hs = Hin[ck * 16384 + (b << 9) + h];
    #pragma unroll 8
    for (int s = 0; s < 32; ++s) {
        float rf = rawF[base + (size_t)s * H_] + bfv;
        float rz = rawZ[base + (size_t)s * H_] + bzv;
        float f = __builtin_amdgcn_rcpf(1.f + __expf(-rf));
        float z = __builtin_amdgcn_rcpf(1.f + __expf(-rz));
        hs = fmaf(f, hs - z, z);
        out[base + (size_t)s * H_] = hs;
    }
}

// ---------------------------------------------------------------------------
extern "C" void kernel_launch(void* const* d_in, const int* in_sizes, int n_in,
                              void* d_out, int out_size, void* d_ws, size_t ws_size,
                              hipStream_t stream) {
    const float* x  = (const float*)d_in[0];
    const float* Wz = (const float*)d_in[2];
    const float* bz = (const float*)d_in[3];
    const float* Wf = (const float*)d_in[4];
    const float* bf = (const float*)d_in[5];
    float* out = (float*)d_out;

    char* ws = (char*)d_ws;
    unsigned short* Ab   = (unsigned short*)(ws);                  // 64 MB
    float*          rawF = (float*)(ws + (size_t)64 * 1024 * 1024); // 64 MB
    unsigned short* Wp   = (unsigned short*)(ws + (size_t)128 * 1024 * 1024); // 2 MB
    // chunk-scan scratch aliases Ab (dead after GEMM)
    float* chA = (float*)(ws);
    float* chC = (float*)(ws + (size_t)2 * 1024 * 1024);
    float* Hin = (float*)(ws + (size_t)4 * 1024 * 1024);
    float* rawZ = out;   // d_out doubles as rawZ scratch

    build_a<<<(M_ * KK_ / 4) / 256, 256, 0, stream>>>(x, Ab);
    pack_w <<<(32 * NN_ * 32) / 256, 256, 0, stream>>>(Wf, Wz, Wp);

    dim3 grid(NN_ / 128, M_ / 128);   // (8, 256)
    mfma_gemm<<<grid, 256, 0, stream>>>(Ab, Wp, rawF, rawZ);

    scan_pass1<<<524288 / 256, 256, 0, stream>>>(rawF, rawZ, bf, bz, chA, chC);
    scan_pass2<<<16384 / 256, 256, 0, stream>>>(chA, chC, Hin);
    scan_pass3<<<524288 / 256, 256, 0, stream>>>(rawF, rawZ, bf, bz, Hin, out);
}

// Round 3
// 258.492 us; speedup vs baseline: 4.2366x; 1.2796x over previous
//
#include <hip/hip_runtime.h>
#include <hip/hip_bf16.h>
#include <cstddef>
#include <cstdint>

// (B,T,I,H,K) = (32,1024,512,512,2)
#define B_  32
#define T_  1024
#define I_  512
#define H_  512
#define M_  (B_ * T_)     // 32768
#define NN_ 1024          // concat F|Z columns
#define TP_ 1025          // padded T rows (row 0 = zeros) per batch

typedef __bf16 bf16x8  __attribute__((ext_vector_type(8)));
typedef float  floatx4 __attribute__((ext_vector_type(4)));

__device__ __forceinline__ unsigned short f2bf(float f) {
    uint32_t u = __float_as_uint(f);
    return (unsigned short)((u + 0x7FFFu + ((u >> 16) & 1u)) >> 16);
}
__device__ __forceinline__ float bf2f_lo(uint32_t p) {   // low bf16 of a packed pair
    return __uint_as_float(p << 16);
}
__device__ __forceinline__ float bf2f_hi(uint32_t p) {   // high bf16
    return __uint_as_float(p & 0xFFFF0000u);
}

#define GLL(src, dst) __builtin_amdgcn_global_load_lds( \
    (const __attribute__((address_space(1))) void*)(src), \
    (__attribute__((address_space(3))) void*)(dst), 16, 0, 0)

// ---------------------------------------------------------------------------
// Fused prep kernel.
//  Part 1 (blocks [0, NB_BUILD)): Ab2p[b][trow][i] bf16; trow==0 -> 0,
//    else x[b][trow-1][i].  4 elements/thread.
//  Part 2 (blocks [NB_BUILD, NB_BUILD+NB_PACK)): pack weights
//    Wp[ksub][n][kw] bf16, ksub=0..31, n: 0..511 F cols | 512..1023 Z cols,
//    kk = ksub*32+kw, tap = kk>>9, i = kk&511; W layout [H][I][2].
// ---------------------------------------------------------------------------
#define NB_BUILD 16400   // 32*1025*512/4/256
#define NB_PACK  4096    // 32*1024*32/256

__global__ __launch_bounds__(256) void prep(const float* __restrict__ x,
                                            const float* __restrict__ Wf,
                                            const float* __restrict__ Wz,
                                            unsigned short* __restrict__ Ab2,
                                            unsigned short* __restrict__ Wp) {
    if (blockIdx.x < NB_BUILD) {
        int g = blockIdx.x * 256 + threadIdx.x;     // 4,198,400 threads
        int idx4 = g << 2;
        int row = idx4 >> 9;                        // 0 .. 32*1025-1
        int col = idx4 & 511;
        int b    = (int)((unsigned)row / TP_);      // compiler magic-div
        int trow = row - b * TP_;
        ushort4 o = make_ushort4(0, 0, 0, 0);
        if (trow > 0) {
            float4 v = *(const float4*)&x[((size_t)b * T_ + (trow - 1)) * I_ + col];
            o.x = f2bf(v.x); o.y = f2bf(v.y); o.z = f2bf(v.z); o.w = f2bf(v.w);
        }
        *(ushort4*)&Ab2[(size_t)idx4] = o;
    } else {
        int e = (blockIdx.x - NB_BUILD) * 256 + threadIdx.x;  // 0..1048575
        int ksub = e >> 15;
        int n    = (e >> 5) & 1023;
        int kw   = e & 31;
        int kk   = ksub * 32 + kw;
        int tap  = kk >> 9;
        int i    = kk & 511;
        int h    = n & 511;
        const float* G = (n < 512) ? Wf : Wz;
        Wp[e] = f2bf(G[h * (I_ * 2) + i * 2 + tap]);
    }
}

// ---------------------------------------------------------------------------
// MFMA GEMM, 128x128 tile, BK=64 (two 32-k sub-tiles per barrier pair).
// K = 2 taps x 512 i, taps realized as +0/+1 row shifts into Ab2p.
// Output raw gates as bf16: n<512 -> rawF, n>=512 -> rawZ.
// XCD-aware block swizzle: xcd = id&7 owns m-tiles [xcd*32, xcd*32+32).
// ---------------------------------------------------------------------------
__global__ __launch_bounds__(256) void mfma_gemm(
        const unsigned short* __restrict__ Ab2,  // [32][1025][512]
        const unsigned short* __restrict__ Wp,   // [32][1024][32]
        unsigned short* __restrict__ rawF,       // [M_][512] bf16
        unsigned short* __restrict__ rawZ) {
    __shared__ unsigned short smem[16384];       // A: [0,8192), B: [8192,16384)

    const int id   = blockIdx.x;                 // 0..2047
    const int xcd  = id & 7;
    const int j    = id >> 3;                    // 0..255
    const int mi   = xcd * 32 + (j >> 3);
    const int ni   = j & 7;
    const int m0   = mi * 128;
    const int n0   = ni * 128;

    const int tid  = threadIdx.x;
    const int lane = tid & 63;
    const int wave = tid >> 6;
    const int wm   = wave >> 1, wn = wave & 1;
    const int lm   = lane & 15, quad = lane >> 4;

    // chunk ids for staging one 8KB sub-tile (512 chunks, 2 per thread)
    const int c0 = wave * 128 + lane;
    const int c1 = c0 + 64;
    const int r0 = c0 >> 2, q0 = (c0 & 3) ^ ((r0 >> 2) & 3);
    const int r1 = c1 >> 2, q1 = (c1 & 3) ^ ((r1 >> 2) & 3);

    const int browBase = (m0 >> 10) * TP_ + (m0 & 1023);   // Ab2p row of t=tile row 0, tap0

    const unsigned short* srcB0 = Wp + (size_t)(n0 + r0) * 32 + q0 * 8;
    const unsigned short* srcB1 = Wp + (size_t)(n0 + r1) * 32 + q1 * 8;

    unsigned short* dA0 = smem + wave * 1024;          // + s*4096
    unsigned short* dA1 = smem + wave * 1024 + 512;
    unsigned short* dB0 = smem + 8192 + wave * 1024;
    unsigned short* dB1 = smem + 8192 + wave * 1024 + 512;

    // fragment element-offsets within a sub-tile (add s*4096 / +8192 for B)
    int offA[4], offB[4];
    #pragma unroll
    for (int r = 0; r < 4; ++r) {
        int ml = wm * 64 + r * 16 + lm;
        offA[r] = (4 * ml + (quad ^ ((ml >> 2) & 3))) * 8;
    }
    #pragma unroll
    for (int c = 0; c < 4; ++c) {
        int nl = wn * 64 + c * 16 + lm;
        offB[c] = 8192 + (4 * nl + (quad ^ ((nl >> 2) & 3))) * 8;
    }

    floatx4 acc[4][4] = {};

    for (int kt2 = 0; kt2 < 16; ++kt2) {
        const int tap = kt2 >> 3;           // 0..1
        const int i0  = (kt2 & 7) * 64;     // i base for this BK=64 slab
        #pragma unroll
        for (int s = 0; s < 2; ++s) {
            const unsigned short* sA0 = Ab2 + (size_t)(browBase + tap + r0) * 512 + i0 + s * 32 + q0 * 8;
            const unsigned short* sA1 = Ab2 + (size_t)(browBase + tap + r1) * 512 + i0 + s * 32 + q1 * 8;
            const size_t wOff = (size_t)(kt2 * 2 + s) * 32768;
            GLL(sA0, dA0 + s * 4096);
            GLL(sA1, dA1 + s * 4096);
            GLL(srcB0 + wOff, dB0 + s * 4096);
            GLL(srcB1 + wOff, dB1 + s * 4096);
        }
        __syncthreads();

        #pragma unroll
        for (int s = 0; s < 2; ++s) {
            bf16x8 af[4], bfr[4];
            #pragma unroll
            for (int r = 0; r < 4; ++r) af[r]  = *(const bf16x8*)(smem + s * 4096 + offA[r]);
            #pragma unroll
            for (int c = 0; c < 4; ++c) bfr[c] = *(const bf16x8*)(smem + s * 4096 + offB[c]);
            #pragma unroll
            for (int r = 0; r < 4; ++r)
                #pragma unroll
                for (int c = 0; c < 4; ++c)
                    acc[r][c] = __builtin_amdgcn_mfma_f32_16x16x32_bf16(
                                    af[r], bfr[c], acc[r][c], 0, 0, 0);
        }
        __syncthreads();
    }

    // epilogue: C/D layout col=lane&15, row=quad*4+reg; store bf16
    unsigned short* base = (n0 < 512) ? rawF : rawZ;
    const int col0 = (n0 & 511) + wn * 64 + lm;
    #pragma unroll
    for (int r = 0; r < 4; ++r) {
        #pragma unroll
        for (int v = 0; v < 4; ++v) {
            const size_t row = (size_t)(m0 + wm * 64 + r * 16 + quad * 4 + v);
            #pragma unroll
            for (int c = 0; c < 4; ++c)
                base[row * H_ + col0 + c * 16] = f2bf(acc[r][c][v]);
        }
    }
}

// ---------------------------------------------------------------------------
// Scan: h[t] = f*h[t-1] + (1-f)*z over T in 32 chunks of 32.
// Raw gates are bf16; each thread handles 2 adjacent h columns.
// ---------------------------------------------------------------------------
__global__ __launch_bounds__(256) void scan_pass1(
        const unsigned short* __restrict__ rawF, const unsigned short* __restrict__ rawZ,
        const float* __restrict__ biasF, const float* __restrict__ biasZ,
        float* __restrict__ chA, float* __restrict__ chC) {
    int g  = blockIdx.x * 256 + threadIdx.x;   // 262144
    int hp = g & 255;
    int b  = (g >> 8) & 31;
    int ck = g >> 13;
    int h0 = hp * 2;
    const float bf0 = biasF[h0], bf1 = biasF[h0 + 1];
    const float bz0 = biasZ[h0], bz1 = biasZ[h0 + 1];
    size_t base = ((size_t)(b * T_ + ck * 32)) * H_ + h0;
    float A0 = 1.f, C0 = 0.f, A1 = 1.f, C1 = 0.f;
    #pragma unroll 8
    for (int s = 0; s < 32; ++s) {
        uint32_t pf = *(const uint32_t*)&rawF[base + (size_t)s * H_];
        uint32_t pz = *(const uint32_t*)&rawZ[base + (size_t)s * H_];
        float f0 = __builtin_amdgcn_rcpf(1.f + __expf(-(bf2f_lo(pf) + bf0)));
        float f1 = __builtin_amdgcn_rcpf(1.f + __expf(-(bf2f_hi(pf) + bf1)));
        float z0 = __builtin_amdgcn_rcpf(1.f + __expf(-(bf2f_lo(pz) + bz0)));
        float z1 = __builtin_amdgcn_rcpf(1.f + __expf(-(bf2f_hi(pz) + bz1)));
        A0 *= f0; C0 = fmaf(f0, C0 - z0, z0);
        A1 *= f1; C1 = fmaf(f1, C1 - z1, z1);
    }
    size_t o = (size_t)ck * 16384 + (b << 9) + h0;
    *(float2*)&chA[o] = make_float2(A0, A1);
    *(float2*)&chC[o] = make_float2(C0, C1);
}

__global__ __launch_bounds__(256) void scan_pass2(
        const float* __restrict__ chA, const float* __restrict__ chC,
        float* __restrict__ Hin) {
    int bh = blockIdx.x * 256 + threadIdx.x;   // 16384
    float H = 0.f;
    #pragma unroll
    for (int ck = 0; ck < 32; ++ck) {
        Hin[ck * 16384 + bh] = H;
        H = fmaf(chA[ck * 16384 + bh], H, chC[ck * 16384 + bh]);
    }
}

__global__ __launch_bounds__(256) void scan_pass3(
        const unsigned short* __restrict__ rawF, const unsigned short* __restrict__ rawZ,
        const float* __restrict__ biasF, const float* __restrict__ biasZ,
        const float* __restrict__ Hin, float* __restrict__ out) {
    int g  = blockIdx.x * 256 + threadIdx.x;
    int hp = g & 255;
    int b  = (g >> 8) & 31;
    int ck = g >> 13;
    int h0 = hp * 2;
    const float bf0 = biasF[h0], bf1 = biasF[h0 + 1];
    const float bz0 = biasZ[h0], bz1 = biasZ[h0 + 1];
    size_t base = ((size_t)(b * T_ + ck * 32)) * H_ + h0;
    float2 hin = *(const float2*)&Hin[(size_t)ck * 16384 + (b << 9) + h0];
    float hs0 = hin.x, hs1 = hin.y;
    #pragma unroll 8
    for (int s = 0; s < 32; ++s) {
        uint32_t pf = *(const uint32_t*)&rawF[base + (size_t)s * H_];
        uint32_t pz = *(const uint32_t*)&rawZ[base + (size_t)s * H_];
        float f0 = __builtin_amdgcn_rcpf(1.f + __expf(-(bf2f_lo(pf) + bf0)));
        float f1 = __builtin_amdgcn_rcpf(1.f + __expf(-(bf2f_hi(pf) + bf1)));
        float z0 = __builtin_amdgcn_rcpf(1.f + __expf(-(bf2f_lo(pz) + bz0)));
        float z1 = __builtin_amdgcn_rcpf(1.f + __expf(-(bf2f_hi(pz) + bz1)));
        hs0 = fmaf(f0, hs0 - z0, z0);
        hs1 = fmaf(f1, hs1 - z1, z1);
        *(float2*)&out[base + (size_t)s * H_] = make_float2(hs0, hs1);
    }
}

// ---------------------------------------------------------------------------
extern "C" void kernel_launch(void* const* d_in, const int* in_sizes, int n_in,
                              void* d_out, int out_size, void* d_ws, size_t ws_size,
                              hipStream_t stream) {
    const float* x  = (const float*)d_in[0];
    const float* Wz = (const float*)d_in[2];
    const float* bz = (const float*)d_in[3];
    const float* Wf = (const float*)d_in[4];
    const float* bf = (const float*)d_in[5];
    float* out = (float*)d_out;

    char* ws = (char*)d_ws;
    unsigned short* Ab2  = (unsigned short*)(ws);                              // 33.6 MB
    unsigned short* rawF = (unsigned short*)(ws + (size_t)34 * 1024 * 1024);   // 32 MB
    unsigned short* rawZ = (unsigned short*)(ws + (size_t)66 * 1024 * 1024);   // 32 MB
    unsigned short* Wp   = (unsigned short*)(ws + (size_t)98 * 1024 * 1024);   // 2 MB
    // chunk-scan scratch aliases Ab2 (dead after GEMM)
    float* chA = (float*)(ws);
    float* chC = (float*)(ws + (size_t)2 * 1024 * 1024);
    float* Hin = (float*)(ws + (size_t)4 * 1024 * 1024);

    prep<<<NB_BUILD + NB_PACK, 256, 0, stream>>>(x, Wf, Wz, Ab2, Wp);

    mfma_gemm<<<2048, 256, 0, stream>>>(Ab2, Wp, rawF, rawZ);

    scan_pass1<<<262144 / 256, 256, 0, stream>>>(rawF, rawZ, bf, bz, chA, chC);
    scan_pass2<<<16384 / 256, 256, 0, stream>>>(chA, chC, Hin);
    scan_pass3<<<262144 / 256, 256, 0, stream>>>(rawF, rawZ, bf, bz, Hin, out);
}

// Round 4
// 224.574 us; speedup vs baseline: 4.8765x; 1.1510x over previous
//
#include <hip/hip_runtime.h>
#include <hip/hip_bf16.h>
#include <cstddef>
#include <cstdint>

// (B,T,I,H,K) = (32,1024,512,512,2)
#define B_  32
#define T_  1024
#define I_  512
#define H_  512
#define M_  (B_ * T_)     // 32768
#define TP_ 1025          // padded T rows (row 0 = zeros) per batch

typedef __bf16 bf16x8  __attribute__((ext_vector_type(8)));
typedef float  floatx4 __attribute__((ext_vector_type(4)));

__device__ __forceinline__ unsigned short f2bf(float f) {
    uint32_t u = __float_as_uint(f);
    return (unsigned short)((u + 0x7FFFu + ((u >> 16) & 1u)) >> 16);
}
__device__ __forceinline__ float bf2f_lo(uint32_t p) { return __uint_as_float(p << 16); }
__device__ __forceinline__ float bf2f_hi(uint32_t p) { return __uint_as_float(p & 0xFFFF0000u); }
__device__ __forceinline__ float sigm(float x) {
    return __builtin_amdgcn_rcpf(1.f + __expf(-x));
}

#define GLL(src, dst) __builtin_amdgcn_global_load_lds( \
    (const __attribute__((address_space(1))) void*)(src), \
    (__attribute__((address_space(3))) void*)(dst), 16, 0, 0)

// ---------------------------------------------------------------------------
// Fused prep kernel.
//  Part 1: Ab2[b][trow][i] bf16; trow==0 -> 0, else x[b][trow-1][i].
//  Part 2: per-gate weight packs WpF/WpZ: Wp[gate][ksub][h][kw] bf16,
//    kk = ksub*32+kw, tap = kk>>9, i = kk&511; W layout [H][I][2].
// ---------------------------------------------------------------------------
#define NB_BUILD 16400   // 32*1025*512/4/256
#define NB_PACK  4096    // 2*32*512*32/256

__global__ __launch_bounds__(256) void prep(const float* __restrict__ x,
                                            const float* __restrict__ Wf,
                                            const float* __restrict__ Wz,
                                            unsigned short* __restrict__ Ab2,
                                            unsigned short* __restrict__ Wp) {
    if (blockIdx.x < NB_BUILD) {
        int g = blockIdx.x * 256 + threadIdx.x;
        int idx4 = g << 2;
        int row = idx4 >> 9;                        // 0 .. 32*1025-1
        int col = idx4 & 511;
        int b    = (int)((unsigned)row / TP_);
        int trow = row - b * TP_;
        ushort4 o = make_ushort4(0, 0, 0, 0);
        if (trow > 0) {
            float4 v = *(const float4*)&x[((size_t)b * T_ + (trow - 1)) * I_ + col];
            o.x = f2bf(v.x); o.y = f2bf(v.y); o.z = f2bf(v.z); o.w = f2bf(v.w);
        }
        *(ushort4*)&Ab2[(size_t)idx4] = o;
    } else {
        int e = (blockIdx.x - NB_BUILD) * 256 + threadIdx.x;  // 0..1048575
        int gate = e >> 19;
        int e2   = e & 524287;
        int ksub = e2 >> 14;
        int h    = (e2 >> 5) & 511;
        int kw   = e2 & 31;
        int kk   = ksub * 32 + kw;
        int tap  = kk >> 9;
        int i    = kk & 511;
        const float* G = gate ? Wz : Wf;
        Wp[e] = f2bf(G[h * (I_ * 2) + i * 2 + tap]);
    }
}

// ---------------------------------------------------------------------------
// Dual-gate MFMA GEMM + fused chunk-composition (old scan_pass1).
// Block tile: 128 m-rows x 128 h-cols, BOTH gates (effective 128x256).
// BK=64 per barrier-pair (two 32-k sub-stages), 64 MFMA/wave per pair.
// Epilogue: store raw bf16 F/Z + compose per-32-t-chunk affine (A,C) -> chA/chC.
// ---------------------------------------------------------------------------
__global__ __launch_bounds__(256, 2) void mfma_gemm(
        const unsigned short* __restrict__ Ab2,  // [32][1025][512]
        const unsigned short* __restrict__ Wp,   // [2][32][512][32]
        const float* __restrict__ biasF,
        const float* __restrict__ biasZ,
        unsigned short* __restrict__ rawF,       // [M_][512] bf16
        unsigned short* __restrict__ rawZ,
        float* __restrict__ chA, float* __restrict__ chC) {
    // per sub-stage s: A [0,4096), BF [4096,8192), BZ [8192,12288) shorts
    __shared__ unsigned short smem[24576];       // 48 KB (2 sub-stages)

    const int id  = blockIdx.x;                  // 0..1023
    const int xcd = id & 7;
    const int j   = id >> 3;                     // 0..127
    const int mi  = xcd * 32 + (j >> 2);
    const int ni  = j & 3;
    const int m0  = mi * 128;
    const int h0  = ni * 128;

    const int tid  = threadIdx.x;
    const int lane = tid & 63;
    const int wave = tid >> 6;
    const int wm   = wave >> 1, wn = wave & 1;
    const int lm   = lane & 15, quad = lane >> 4;

    // staging chunk ids (512 chunks/region; wave covers 128: lane, lane+64)
    const int c0 = wave * 128 + lane;
    const int c1 = c0 + 64;
    const int r0 = c0 >> 2, q0 = (c0 & 3) ^ ((r0 >> 2) & 3);
    const int r1 = c1 >> 2, q1 = (c1 & 3) ^ ((r1 >> 2) & 3);

    const int browBase = (m0 >> 10) * TP_ + (m0 & 1023);

    const unsigned short* WpF = Wp;
    const unsigned short* WpZ = Wp + 524288;

    const unsigned short* pA0 = Ab2 + (size_t)(browBase + r0) * 512 + q0 * 8;
    const unsigned short* pA1 = Ab2 + (size_t)(browBase + r1) * 512 + q1 * 8;
    const unsigned short* pF0 = WpF + (size_t)(h0 + r0) * 32 + q0 * 8;
    const unsigned short* pF1 = WpF + (size_t)(h0 + r1) * 32 + q1 * 8;
    const unsigned short* pZ0 = WpZ + (size_t)(h0 + r0) * 32 + q0 * 8;
    const unsigned short* pZ1 = WpZ + (size_t)(h0 + r1) * 32 + q1 * 8;

    unsigned short* dA0 = smem + wave * 1024;         // + s*12288
    unsigned short* dA1 = smem + wave * 1024 + 512;
    unsigned short* dF0 = smem + 4096 + wave * 1024;
    unsigned short* dF1 = smem + 4096 + wave * 1024 + 512;
    unsigned short* dZ0 = smem + 8192 + wave * 1024;
    unsigned short* dZ1 = smem + 8192 + wave * 1024 + 512;

    // fragment element-offsets within a sub-stage
    int offA[4], offB[4];
    #pragma unroll
    for (int r = 0; r < 4; ++r) {
        int ml = wm * 64 + r * 16 + lm;
        offA[r] = (4 * ml + (quad ^ ((ml >> 2) & 3))) * 8;
    }
    #pragma unroll
    for (int c = 0; c < 4; ++c) {
        int nl = wn * 64 + c * 16 + lm;
        offB[c] = 4096 + (4 * nl + (quad ^ ((nl >> 2) & 3))) * 8;
    }

    floatx4 accF[4][4] = {};
    floatx4 accZ[4][4] = {};

    for (int kt2 = 0; kt2 < 16; ++kt2) {
        const int tap = kt2 >> 3;
        const int i0  = (kt2 & 7) * 64;
        #pragma unroll
        for (int s = 0; s < 2; ++s) {
            const int aoff = tap * 512 + i0 + s * 32;
            const size_t woff = (size_t)(kt2 * 2 + s) * 16384;
            const int ls = s * 12288;
            GLL(pA0 + aoff, dA0 + ls);
            GLL(pA1 + aoff, dA1 + ls);
            GLL(pF0 + woff, dF0 + ls);
            GLL(pF1 + woff, dF1 + ls);
            GLL(pZ0 + woff, dZ0 + ls);
            GLL(pZ1 + woff, dZ1 + ls);
        }
        __syncthreads();

        #pragma unroll
        for (int s = 0; s < 2; ++s) {
            const int ls = s * 12288;
            bf16x8 af[4], bF[4], bZ[4];
            #pragma unroll
            for (int r = 0; r < 4; ++r) af[r] = *(const bf16x8*)(smem + ls + offA[r]);
            #pragma unroll
            for (int c = 0; c < 4; ++c) {
                bF[c] = *(const bf16x8*)(smem + ls + offB[c]);
                bZ[c] = *(const bf16x8*)(smem + ls + offB[c] + 4096);
            }
            #pragma unroll
            for (int r = 0; r < 4; ++r) {
                #pragma unroll
                for (int c = 0; c < 4; ++c) {
                    accF[r][c] = __builtin_amdgcn_mfma_f32_16x16x32_bf16(
                                    af[r], bF[c], accF[r][c], 0, 0, 0);
                    accZ[r][c] = __builtin_amdgcn_mfma_f32_16x16x32_bf16(
                                    af[r], bZ[c], accZ[r][c], 0, 0, 0);
                }
            }
        }
        __syncthreads();
    }

    // ---- epilogue ----
    // biases for this lane's 4 columns
    float bfv[4], bzv[4];
    #pragma unroll
    for (int c = 0; c < 4; ++c) {
        int hc = h0 + wn * 64 + c * 16 + lm;
        bfv[c] = biasF[hc];
        bzv[c] = biasZ[hc];
    }

    // store raw bf16 + per-(r,c) 4-step affine segment into LDS
    float2* seg = (float2*)smem;   // 4096 float2 = 32 KB (staging is dead)
    const int col0 = h0 + wn * 64 + lm;
    #pragma unroll
    for (int r = 0; r < 4; ++r) {
        #pragma unroll
        for (int c = 0; c < 4; ++c) {
            float A = 1.f, C = 0.f;
            #pragma unroll
            for (int v = 0; v < 4; ++v) {
                const size_t row = (size_t)(m0 + wm * 64 + r * 16 + quad * 4 + v);
                float rf = accF[r][c][v];
                float rz = accZ[r][c][v];
                rawF[row * H_ + col0 + c * 16] = f2bf(rf);
                rawZ[row * H_ + col0 + c * 16] = f2bf(rz);
                float f = sigm(rf + bfv[c]);
                float z = sigm(rz + bzv[c]);
                A *= f;
                C = fmaf(f, C - z, z);
            }
            seg[(((wave * 4 + r) * 4 + quad) * 4 + c) * 16 + lm] = make_float2(A, C);
        }
    }
    __syncthreads();

    // compose 8 segments -> one (A,C) per (chunk, h); 512 pairs / 256 thr
    const int b   = m0 >> 10;
    const int ckb = (m0 & 1023) >> 5;
    #pragma unroll
    for (int pp = 0; pp < 2; ++pp) {
        int p  = tid + pp * 256;
        int ck = p >> 7, hh = p & 127;
        int wv = ((ck >> 1) << 1) + (hh >> 6);
        int cc = (hh >> 4) & 3, lmm = hh & 15;
        float A = 1.f, C = 0.f;
        #pragma unroll
        for (int s = 0; s < 8; ++s) {
            int r = ((ck & 1) << 1) + (s >> 2), q = s & 3;
            float2 sc = seg[(((wv * 4 + r) * 4 + q) * 4 + cc) * 16 + lmm];
            C = fmaf(sc.x, C, sc.y);
            A *= sc.x;
        }
        size_t o = (size_t)(ckb + ck) * 16384 + (b << 9) + h0 + hh;
        chA[o] = A;
        chC[o] = C;
    }
}

// ---------------------------------------------------------------------------
// Pass 2: scan the 32 chunk compositions per (b,h); Hin[ck] = h before chunk.
// ---------------------------------------------------------------------------
__global__ __launch_bounds__(256) void scan_pass2(
        const float* __restrict__ chA, const float* __restrict__ chC,
        float* __restrict__ Hin) {
    int bh = blockIdx.x * 256 + threadIdx.x;   // 16384
    float H = 0.f;
    #pragma unroll
    for (int ck = 0; ck < 32; ++ck) {
        Hin[ck * 16384 + bh] = H;
        H = fmaf(chA[ck * 16384 + bh], H, chC[ck * 16384 + bh]);
    }
}

// Pass 3: replay chunk with correct h_in, write hidden (fp32 out).
__global__ __launch_bounds__(256) void scan_pass3(
        const unsigned short* __restrict__ rawF, const unsigned short* __restrict__ rawZ,
        const float* __restrict__ biasF, const float* __restrict__ biasZ,
        const float* __restrict__ Hin, float* __restrict__ out) {
    int g  = blockIdx.x * 256 + threadIdx.x;
    int hp = g & 255;
    int b  = (g >> 8) & 31;
    int ck = g >> 13;
    int h0 = hp * 2;
    const float bf0 = biasF[h0], bf1 = biasF[h0 + 1];
    const float bz0 = biasZ[h0], bz1 = biasZ[h0 + 1];
    size_t base = ((size_t)(b * T_ + ck * 32)) * H_ + h0;
    float2 hin = *(const float2*)&Hin[(size_t)ck * 16384 + (b << 9) + h0];
    float hs0 = hin.x, hs1 = hin.y;
    #pragma unroll 8
    for (int s = 0; s < 32; ++s) {
        uint32_t pf = *(const uint32_t*)&rawF[base + (size_t)s * H_];
        uint32_t pz = *(const uint32_t*)&rawZ[base + (size_t)s * H_];
        float f0 = sigm(bf2f_lo(pf) + bf0);
        float f1 = sigm(bf2f_hi(pf) + bf1);
        float z0 = sigm(bf2f_lo(pz) + bz0);
        float z1 = sigm(bf2f_hi(pz) + bz1);
        hs0 = fmaf(f0, hs0 - z0, z0);
        hs1 = fmaf(f1, hs1 - z1, z1);
        *(float2*)&out[base + (size_t)s * H_] = make_float2(hs0, hs1);
    }
}

// ---------------------------------------------------------------------------
extern "C" void kernel_launch(void* const* d_in, const int* in_sizes, int n_in,
                              void* d_out, int out_size, void* d_ws, size_t ws_size,
                              hipStream_t stream) {
    const float* x  = (const float*)d_in[0];
    const float* Wz = (const float*)d_in[2];
    const float* bz = (const float*)d_in[3];
    const float* Wf = (const float*)d_in[4];
    const float* bf = (const float*)d_in[5];
    float* out = (float*)d_out;

    char* ws = (char*)d_ws;
    unsigned short* Ab2  = (unsigned short*)(ws);                               // 33.6 MB
    unsigned short* rawF = (unsigned short*)(ws + (size_t)34  * 1024 * 1024);   // 32 MB
    unsigned short* rawZ = (unsigned short*)(ws + (size_t)66  * 1024 * 1024);   // 32 MB
    unsigned short* Wp   = (unsigned short*)(ws + (size_t)98  * 1024 * 1024);   // 2 MB
    float*          chA  = (float*)(ws + (size_t)100 * 1024 * 1024);            // 2 MB
    float*          chC  = (float*)(ws + (size_t)102 * 1024 * 1024);            // 2 MB
    float*          Hin  = (float*)(ws + (size_t)104 * 1024 * 1024);            // 2 MB

    prep<<<NB_BUILD + NB_PACK, 256, 0, stream>>>(x, Wf, Wz, Ab2, Wp);

    mfma_gemm<<<1024, 256, 0, stream>>>(Ab2, Wp, bf, bz, rawF, rawZ, chA, chC);

    scan_pass2<<<16384 / 256, 256, 0, stream>>>(chA, chC, Hin);
    scan_pass3<<<262144 / 256, 256, 0, stream>>>(rawF, rawZ, bf, bz, Hin, out);
}